// Round 14
// baseline (132.869 us; speedup 1.0000x reference)
//
#include <hip/hip_runtime.h>
#include <math.h>

#define NN 588
#define EE 9408
#define HD 64
#define NBLK 64
#define NTHR 1024
#define NWAVE (NTHR/64)   // 16
#define GXROWS (192/NBLK) // 3
#define ELLW 64           // ELL row width (u16 entries), stride 128 B
#define NEGS 0.01f
#define THRESHV 0.999f
#define MAGIC 0x51CAFE17u
#define DROW NN

struct Ctrl {
  unsigned ready;  unsigned pad0[15];
  unsigned xflags[NBLK*16];   // one 64B line per block (4096 B at NBLK=64)
};

__device__ __forceinline__ float lrelu(float v){ return v >= 0.f ? v : NEGS*v; }
__device__ __forceinline__ float sigm(float v){ return 1.f/(1.f+expf(-v)); }
__device__ __forceinline__ float rdlane(float v, int l){
  return __int_as_float(__builtin_amdgcn_readlane(__float_as_int(v), l));
}
__device__ __forceinline__ float wredsum(float v){
  v += __shfl_down(v,32); v += __shfl_down(v,16); v += __shfl_down(v,8);
  v += __shfl_down(v,4);  v += __shfl_down(v,2);  v += __shfl_down(v,1);
  return v;  // valid on lane 0
}
// device-coherent (LLC) access: bypasses non-coherent per-XCD L2, no fences needed
__device__ __forceinline__ void stga(float* p, float v){
  __hip_atomic_store(p, v, __ATOMIC_RELAXED, __HIP_MEMORY_SCOPE_AGENT);
}
__device__ __forceinline__ float ldga(const float* p){
  return __hip_atomic_load(p, __ATOMIC_RELAXED, __HIP_MEMORY_SCOPE_AGENT);
}
__device__ __forceinline__ void stgau(unsigned* p, unsigned v){
  __hip_atomic_store(p, v, __ATOMIC_RELAXED, __HIP_MEMORY_SCOPE_AGENT);
}
__device__ __forceinline__ unsigned ldgau(const unsigned* p){
  return __hip_atomic_load(p, __ATOMIC_RELAXED, __HIP_MEMORY_SCOPE_AGENT);
}
__device__ __forceinline__ void sink4(float4 v){
  asm volatile("" :: "v"(v.x), "v"(v.y), "v"(v.z), "v"(v.w));
}
__device__ __forceinline__ void prefetch_region(const float* p0, int nfloats, int t, int T){
  const float4* p = (const float4*)p0;
  const int n = nfloats >> 2;
  for (int base = t; base < n; base += T*8) {
    float4 v[8];
    #pragma unroll
    for (int u = 0; u < 8; ++u) { int i = base + u*T; if (i >= n) i = n - 1; v[u] = p[i]; }
    #pragma unroll
    for (int u = 0; u < 8; ++u) sink4(v[u]);
  }
}

// ---- split grid barrier: all-to-all flags (R7/R11/R12/R13-proven) ----
__device__ __forceinline__ void barrive(unsigned* flags, int bid, unsigned gen) {
  __syncthreads();                       // all waves' agent stores drained
  if (threadIdx.x == 0) {
    __hip_atomic_store(&flags[bid*16], gen, __ATOMIC_RELEASE, __HIP_MEMORY_SCOPE_AGENT);
  }
}
__device__ __forceinline__ void bwait(unsigned* flags, unsigned gen) {
  if ((threadIdx.x >> 6) == 0) {
    int lane = threadIdx.x & 63;
    const unsigned* fp = &flags[lane*16];
    long bail = 0;
    for (;;) {
      int ok = (lane >= NBLK) ? 1 :
               (__hip_atomic_load(fp, __ATOMIC_RELAXED, __HIP_MEMORY_SCOPE_AGENT) >= gen);
      if (__all(ok)) break;
      __builtin_amdgcn_s_sleep(1);
      if (++bail > (1L<<15)) break;      // ~3ms worst case; fast-fail, never hang
    }
    asm volatile("" ::: "memory");
  }
  __syncthreads();
}

__global__ __launch_bounds__(NTHR)
void lastgcn_kernel(const float* __restrict__ feat, const int* __restrict__ src,
                    const int* __restrict__ dst,
                    const float* __restrict__ W1, const float* __restrict__ b1,
                    const float* __restrict__ W2, const float* __restrict__ b2,
                    const float* __restrict__ W3, const float* __restrict__ b3,
                    const float* __restrict__ W5, const float* __restrict__ b5,
                    const float* __restrict__ wi, const float* __restrict__ wh,
                    const float* __restrict__ bi, const float* __restrict__ bh,
                    const float* __restrict__ w_end, const float* __restrict__ b_end,
                    const int* __restrict__ capp,
                    float* __restrict__ out, Ctrl* ctrl,
                    float* __restrict__ x0g, float* __restrict__ x1g,
                    float* __restrict__ ypub, float* __restrict__ gxpub,
                    unsigned* __restrict__ ellG, unsigned* __restrict__ degG) {
  const int tid  = threadIdx.x;
  const int lane = tid & 63;
  const int w    = tid >> 6;
  const int bid  = blockIdx.x;
  const int nbeg = (NN*bid)/NBLK;
  const int nend = (NN*(bid+1))/NBLK;
  const int cnt  = nend - nbeg;          // 9 or 10
  const int r0   = bid*GXROWS;

  __shared__ float  W2L[64*64];               // 16384 B
  __shared__ unsigned short ellF[NN*ELLW];    // 75264 B (full ELL table)
  __shared__ int    degF[NN];                 // 2352 B (padded lengths)
  __shared__ float  yF[NN+1];
  __shared__ float  inpF[NN];
  __shared__ float  ghL[192];
  __shared__ float4 f4L[16];

  // ---- init gate (one-time per launch; R7-proven protocol) ----
  if (bid == 0) {
    if (tid < HD) { stga(&x0g[DROW*HD + tid], 0.f); stga(&x1g[DROW*HD + tid], 0.f); }
    if (tid == 64) stga(&ypub[NN], 0.f);
    if (tid == 65) stga(&ypub[(NN+1) + NN], 0.f);
    for (int i2 = tid; i2 < NBLK*16; i2 += NTHR) {   // zero xflags (1024 words)
      ((unsigned*)ctrl)[16 + i2] = 0u;
    }
    __syncthreads();
    if (tid == 0) {
      __threadfence();
      __hip_atomic_store(&ctrl->ready, MAGIC, __ATOMIC_RELEASE, __HIP_MEMORY_SCOPE_AGENT);
    }
  } else if (tid == 0) {
    long bail = 0;
    while (__hip_atomic_load(&ctrl->ready, __ATOMIC_RELAXED, __HIP_MEMORY_SCOPE_AGENT) != MAGIC) {
      __builtin_amdgcn_s_sleep(1);
      if (++bail > (1L<<20)) break;
    }
    __threadfence();   // one-time inv; precedes all data reads
  }
  __syncthreads();

  // ---- ELL build: filter OWN edges only (~150 of 9408); W2 staging ----
  if (tid < cnt) degF[nbeg + tid] = 0;
  for (int i = tid; i < 1024; i += NTHR) ((float4*)W2L)[i] = ((const float4*)W2)[i];
  __syncthreads();
  {
    const int4* s4 = (const int4*)src;
    const int4* d4 = (const int4*)dst;
    for (int e4 = tid; e4 < EE/4; e4 += NTHR) {   // EE = 4*2352 exactly
      int4 s = s4[e4], d = d4[e4];
      if (d.x >= nbeg && d.x < nend) { int p = atomicAdd(&degF[d.x],1); if (p < ELLW) ellF[(size_t)d.x*ELLW + p] = (unsigned short)s.x; }
      if (d.y >= nbeg && d.y < nend) { int p = atomicAdd(&degF[d.y],1); if (p < ELLW) ellF[(size_t)d.y*ELLW + p] = (unsigned short)s.y; }
      if (d.z >= nbeg && d.z < nend) { int p = atomicAdd(&degF[d.z],1); if (p < ELLW) ellF[(size_t)d.z*ELLW + p] = (unsigned short)s.z; }
      if (d.w >= nbeg && d.w < nend) { int p = atomicAdd(&degF[d.w],1); if (p < ELLW) ellF[(size_t)d.w*ELLW + p] = (unsigned short)s.w; }
    }
    // warm LLC: disjoint wi slices across blocks + w_end
    prefetch_region(wi + r0*NN, GXROWS*NN, tid, NTHR);
    prefetch_region(w_end, 64, tid, NTHR);
  }
  __syncthreads();
  // ---- pad own rows to x8 with DROW; publish own rows + degrees ----
  if (tid < cnt) {
    int n = nbeg + tid;
    int dg = degF[n]; if (dg > ELLW) dg = ELLW;
    int pd = (dg + 7) & ~7; if (pd > ELLW) pd = ELLW;
    unsigned short* row = ellF + (size_t)n*ELLW;
    for (int j = dg; j < pd; ++j) row[j] = (unsigned short)DROW;
    degF[n] = pd;
  }
  __syncthreads();
  {
    const unsigned* e32 = (const unsigned*)ellF;
    for (int i = tid; i < cnt*32; i += NTHR) {
      int rrow = nbeg + (i >> 5), word = i & 31;
      stgau(&ellG[(size_t)rrow*32 + word], e32[(size_t)rrow*32 + word]);
    }
    if (tid < cnt) stgau(&degG[nbeg + tid], (unsigned)degF[nbeg + tid]);
  }

  // ---- conv1 on my partition (own ELL rows, built locally) ----
  if (tid < cnt) {
    int n = nbeg + tid;
    const unsigned short* row = ellF + (size_t)n*ELLW;
    int len = degF[n];
    float fx=0.f, fy=0.f, fz=0.f, fw2=0.f;
    for (int k = 0; k < len; k += 8) {
      uint4 q = *(const uint4*)(row + k);
      int id[8] = { (int)(q.x & 0xFFFF), (int)(q.x >> 16), (int)(q.y & 0xFFFF), (int)(q.y >> 16),
                    (int)(q.z & 0xFFFF), (int)(q.z >> 16), (int)(q.w & 0xFFFF), (int)(q.w >> 16) };
      float4 tv[8]; float m[8];
      #pragma unroll
      for (int u = 0; u < 8; ++u) {
        int valid = id[u] < NN;
        m[u] = valid ? 1.f : 0.f;
        tv[u] = *(const float4*)(feat + (valid ? id[u] : 0)*4);
      }
      #pragma unroll
      for (int u = 0; u < 8; ++u) { fx += m[u]*tv[u].x; fy += m[u]*tv[u].y; fz += m[u]*tv[u].z; fw2 += m[u]*tv[u].w; }
    }
    f4L[tid] = make_float4(fx, fy, fz, fw2);
  }
  __syncthreads();
  const float W3r = W3[lane];
  for (int i = w; i < cnt; i += NWAVE) {
    int n = nbeg + i; float4 f = f4L[i];
    float v = b1[lane] + f.x*W1[lane] + f.y*W1[64+lane] + f.z*W1[128+lane] + f.w*W1[192+lane];
    v = lrelu(v);
    stga(&x0g[n*HD + lane], v);
    float yv = wredsum(v * W3r);
    if (lane == 0) stga(&ypub[n], yv);   // buffer 0
  }
  barrive(ctrl->xflags, bid, 1u);        // X0 + y0 + ELL rows published

  const float b3v  = b3[0];
  const float b2r  = b2[lane];
  const float bend0 = b_end[0];
  const float wer  = w_end[lane];
  const int cap = capp[0];
  float* xc = x0g;
  float* xn = x1g;

  // GRU state, replicated in registers in EVERY wave (uniform => uniform break)
  float stj = 0.f;      // frozen state component for this lane
  float s_run = 0.f;    // running sigmoid sum
  float fprobr = 0.f;   // last committed prob
  int   nsteps = 0;     // committed step count

  // ---- single-barrier pipelined loop (R13 structure) ----
  for (int k = 0; ; ++k) {
    bwait(ctrl->xflags, (unsigned)(k+1));          // X_k, y_k, gx_{k-1} visible

    if (k == 0) {
      // one-time: assemble full ELL table from all blocks' published rows
      unsigned* e32 = (unsigned*)ellF;
      for (int i = tid; i < NN*32; i += NTHR) e32[i] = ldgau(&ellG[i]);
      for (int i = tid; i < NN; i += NTHR) degF[i] = (int)ldgau(&degG[i]);
      __syncthreads();
    }

    const float* yp = ypub + (k&1)*(NN+1);
    // issue yF loads early (independent of GRU)
    for (int i = tid; i <= NN; i += NTHR) yF[i] = ldga(&yp[i]);

    if (k >= 1) {
      const float* gxp = gxpub + ((k-1)&1)*192;
      int j = lane;
      float gxr = ldga(&gxp[j]), gxz = ldga(&gxp[64+j]), gxn2 = ldga(&gxp[128+j]);
      if (k == 1) {
        float r  = sigm(gxr + bh[j]);
        float z  = sigm(gxz + bh[64+j]);
        float n2 = tanhf(gxn2 + r*bh[128+j]);
        float st = (1.f - z)*n2;                   // h0 = 0
        stj = st;
        float t2 = wredsum(st * wer);
        float pr = sigm(rdlane(t2,0) + bend0);
        s_run = pr; fprobr = pr; nsteps = 0;
        // ghL computed after this iteration's barrive (off critical path)
      } else {
        float r  = sigm(gxr + ghL[j]);
        float z  = sigm(gxz + ghL[64+j]);
        float n2 = tanhf(gxn2 + r*ghL[128+j]);
        float st = (1.f - z)*n2 + z*stj;           // frozen state
        float t2 = wredsum(st * wer);
        float pr = sigm(rdlane(t2,0) + bend0);
        s_run += pr; fprobr = pr; nsteps = k-1;
      }
      if (s_run >= THRESHV || k == cap+1) break;   // uniform everywhere
    }

    // ---- conv2: X_{k+1} = lrelu(conv(X_k, W2)), publish y_{k+1} ----
    if (k < cap) {
      float* ypn = ypub + ((k+1)&1)*(NN+1);
      for (int i = w; i < cnt; i += NWAVE) {       // cnt<=10: one node/wave
        int n = nbeg + i;
        const unsigned short* row = ellF + (size_t)n*ELLW;
        int len = degF[n];
        float acc = 0.f;
        for (int kk = 0; kk < len; kk += 8) {
          uint4 q = *(const uint4*)(row + kk);
          acc += ldga(&xc[(int)(q.x & 0xFFFF)*HD + lane]) + ldga(&xc[(int)(q.x >> 16)*HD + lane]);
          acc += ldga(&xc[(int)(q.y & 0xFFFF)*HD + lane]) + ldga(&xc[(int)(q.y >> 16)*HD + lane]);
          acc += ldga(&xc[(int)(q.z & 0xFFFF)*HD + lane]) + ldga(&xc[(int)(q.z >> 16)*HD + lane]);
          acc += ldga(&xc[(int)(q.w & 0xFFFF)*HD + lane]) + ldga(&xc[(int)(q.w >> 16)*HD + lane]);
        }
        float a0=0.f,a1=0.f,a2=0.f,a3=0.f;
        #pragma unroll
        for (int l = 0; l < 64; l += 4) {
          a0 = fmaf(rdlane(acc,l+0), W2L[(l+0)*64 + lane], a0);
          a1 = fmaf(rdlane(acc,l+1), W2L[(l+1)*64 + lane], a1);
          a2 = fmaf(rdlane(acc,l+2), W2L[(l+2)*64 + lane], a2);
          a3 = fmaf(rdlane(acc,l+3), W2L[(l+3)*64 + lane], a3);
        }
        float v = lrelu(b2r + (a0+a1)+(a2+a3));
        stga(&xn[n*HD + lane], v);
        float yv = wredsum(v * W3r);
        if (lane == 0) stga(&ypn[n], yv);
      }
    }
    __syncthreads();                               // yF complete + conv2 done

    // ---- inp_k: all nodes from yF via full ELL ----
    for (int n = tid; n < NN; n += NTHR) {
      const unsigned short* row = ellF + (size_t)n*ELLW;
      int len = degF[n];
      float a = 0.f;
      for (int kk = 0; kk < len; kk += 8) {
        uint4 q = *(const uint4*)(row + kk);
        a += yF[q.x & 0xFFFF] + yF[q.x >> 16] + yF[q.y & 0xFFFF] + yF[q.y >> 16];
        a += yF[q.z & 0xFFFF] + yF[q.z >> 16] + yF[q.w & 0xFFFF] + yF[q.w >> 16];
      }
      inpF[n] = lrelu(a + b3v);
    }
    __syncthreads();

    // ---- gx_k: my 3 rows -> publish ----
    {
      float* gxp = gxpub + (k&1)*192;
      const float4* inp4 = (const float4*)inpF;   // 147 float4s
      for (int rr = w; rr < GXROWS; rr += NWAVE) {
        const float4* row4 = (const float4*)(wi + (r0 + rr)*NN);
        float p = 0.f;
        #pragma unroll
        for (int kk = 0; kk < 3; ++kk) {
          int c = lane + (kk << 6);
          if (c < 147) {
            float4 a = row4[c], b = inp4[c];
            p += a.x*b.x + a.y*b.y + a.z*b.z + a.w*b.w;
          }
        }
        p = wredsum(p);
        if (lane == 0) stga(&gxp[r0 + rr], p + bi[r0 + rr]);
      }
    }

    barrive(ctrl->xflags, bid, (unsigned)(k+2));   // X_{k+1}, y_{k+1}, gx_k published

    // one-time gh for frozen state, off the critical path (first use: k=2's GRU)
    if (k == 1) {
      for (int rr = w; rr < 192; rr += NWAVE) {
        float p = wredsum(wh[rr*64 + lane] * stj);
        if (lane == 0) ghL[rr] = p + bh[rr];
      }
    }
    { float* t = xc; xc = xn; xn = t; }            // commit X_{k+1}
  }

  // ---- final conv on my partition (final X = X_{k-1} = xn) ----
  float* xf = xn;
  for (int i = w; i < cnt; i += NWAVE) {
    int n = nbeg + i;
    const unsigned short* row = ellF + (size_t)n*ELLW;
    int len = degF[n];
    float acc = 0.f;
    for (int k = 0; k < len; k += 8) {
      uint4 q = *(const uint4*)(row + k);
      acc += ldga(&xf[(int)(q.x & 0xFFFF)*HD + lane]) + ldga(&xf[(int)(q.x >> 16)*HD + lane]);
      acc += ldga(&xf[(int)(q.y & 0xFFFF)*HD + lane]) + ldga(&xf[(int)(q.y >> 16)*HD + lane]);
      acc += ldga(&xf[(int)(q.z & 0xFFFF)*HD + lane]) + ldga(&xf[(int)(q.z >> 16)*HD + lane]);
      acc += ldga(&xf[(int)(q.w & 0xFFFF)*HD + lane]) + ldga(&xf[(int)(q.w >> 16)*HD + lane]);
    }
    float p0 = wredsum(acc * W5[lane*3 + 0]);
    float p1 = wredsum(acc * W5[lane*3 + 1]);
    float p2 = wredsum(acc * W5[lane*3 + 2]);
    if (lane == 0) {
      out[n*3 + 0] = p0 + b5[0];
      out[n*3 + 1] = p1 + b5[1];
      out[n*3 + 2] = p2 + b5[2];
    }
  }
  if (bid == 0 && tid == 0) {
    out[NN*3]     = (float)nsteps;  // counter
    out[NN*3 + 1] = fprobr;         // fprob
  }
}

extern "C" void kernel_launch(void* const* d_in, const int* in_sizes, int n_in,
                              void* d_out, int out_size, void* d_ws, size_t ws_size,
                              hipStream_t stream) {
  const float* feat  = (const float*)d_in[0];
  const int*   src   = (const int*)d_in[1];
  const int*   dst   = (const int*)d_in[2];
  const float* W1    = (const float*)d_in[3];
  const float* b1    = (const float*)d_in[4];
  const float* W2    = (const float*)d_in[5];
  const float* b2    = (const float*)d_in[6];
  const float* W3    = (const float*)d_in[7];
  const float* b3    = (const float*)d_in[8];
  const float* W5    = (const float*)d_in[9];
  const float* b5    = (const float*)d_in[10];
  const float* wi    = (const float*)d_in[11];
  const float* wh    = (const float*)d_in[12];
  const float* bi    = (const float*)d_in[13];
  const float* bh    = (const float*)d_in[14];
  const float* w_end = (const float*)d_in[15];
  const float* b_end = (const float*)d_in[16];
  const int*   capp  = (const int*)d_in[17];

  float* out = (float*)d_out;
  char* wsb = (char*)d_ws;
  Ctrl*  ctrl   = (Ctrl*)wsb;                 // 64 + 4096 B at NBLK=64
  float* x0g    = (float*)(wsb + 8192);
  float* x1g    = x0g + (size_t)(NN+1)*HD;
  float* ypub   = x1g + (size_t)(NN+1)*HD;
  float* gxpub  = ypub + 2*(NN+1);
  unsigned* ellG = (unsigned*)(gxpub + 2*192); // NN*32 u32 = 75264 B
  unsigned* degG = ellG + (size_t)NN*32;       // NN u32

  lastgcn_kernel<<<dim3(NBLK), dim3(NTHR), 0, stream>>>(
      feat, src, dst, W1, b1, W2, b2, W3, b3, W5, b5,
      wi, wh, bi, bh, w_end, b_end, capp, out,
      ctrl, x0g, x1g, ypub, gxpub, ellG, degG);
}

// Round 15
// 125.483 us; speedup vs baseline: 1.0589x; 1.0589x over previous
//
#include <hip/hip_runtime.h>
#include <math.h>

#define NN 588
#define EE 9408
#define HD 64
#define NBLK 64
#define NTHR 1024
#define NWAVE (NTHR/64)   // 16
#define GXROWS (192/NBLK) // 3
#define NEGS 0.01f
#define THRESHV 0.999f
#define MAGIC 0x51CAFE17u
#define DROW NN
#define EPADCAP 13536     // >= 9408 + 588*7

struct Ctrl {
  unsigned ready;  unsigned pad0[15];
  unsigned xflags[NBLK*16];   // one 64B line per block (4096 B at NBLK=64)
};

__device__ __forceinline__ float lrelu(float v){ return v >= 0.f ? v : NEGS*v; }
__device__ __forceinline__ float sigm(float v){ return 1.f/(1.f+expf(-v)); }
__device__ __forceinline__ float rdlane(float v, int l){
  return __int_as_float(__builtin_amdgcn_readlane(__float_as_int(v), l));
}
__device__ __forceinline__ float wredsum(float v){
  v += __shfl_down(v,32); v += __shfl_down(v,16); v += __shfl_down(v,8);
  v += __shfl_down(v,4);  v += __shfl_down(v,2);  v += __shfl_down(v,1);
  return v;  // valid on lane 0
}
// device-coherent (LLC) access: bypasses non-coherent per-XCD L2, no fences needed
__device__ __forceinline__ void stga(float* p, float v){
  __hip_atomic_store(p, v, __ATOMIC_RELAXED, __HIP_MEMORY_SCOPE_AGENT);
}
__device__ __forceinline__ float ldga(const float* p){
  return __hip_atomic_load(p, __ATOMIC_RELAXED, __HIP_MEMORY_SCOPE_AGENT);
}
__device__ __forceinline__ void sink4(float4 v){
  asm volatile("" :: "v"(v.x), "v"(v.y), "v"(v.z), "v"(v.w));
}
__device__ __forceinline__ void prefetch_region(const float* p0, int nfloats, int t, int T){
  const float4* p = (const float4*)p0;
  const int n = nfloats >> 2;
  for (int base = t; base < n; base += T*8) {
    float4 v[8];
    #pragma unroll
    for (int u = 0; u < 8; ++u) { int i = base + u*T; if (i >= n) i = n - 1; v[u] = p[i]; }
    #pragma unroll
    for (int u = 0; u < 8; ++u) sink4(v[u]);
  }
}

// ---- split grid barrier: all-to-all flags (R7/R11/R12/R13-proven) ----
__device__ __forceinline__ void barrive(unsigned* flags, int bid, unsigned gen) {
  __syncthreads();                       // all waves' agent stores drained
  if (threadIdx.x == 0) {
    __hip_atomic_store(&flags[bid*16], gen, __ATOMIC_RELEASE, __HIP_MEMORY_SCOPE_AGENT);
  }
}
__device__ __forceinline__ void bwait(unsigned* flags, unsigned gen) {
  if ((threadIdx.x >> 6) == 0) {
    int lane = threadIdx.x & 63;
    const unsigned* fp = &flags[lane*16];
    long bail = 0;
    for (;;) {
      int ok = (lane >= NBLK) ? 1 :
               (__hip_atomic_load(fp, __ATOMIC_RELAXED, __HIP_MEMORY_SCOPE_AGENT) >= gen);
      if (__all(ok)) break;
      __builtin_amdgcn_s_sleep(1);
      if (++bail > (1L<<15)) break;      // ~3ms worst case; fast-fail, never hang
    }
    asm volatile("" ::: "memory");
  }
  __syncthreads();
}

__global__ __launch_bounds__(NTHR)
void lastgcn_kernel(const float* __restrict__ feat, const int* __restrict__ src,
                    const int* __restrict__ dst,
                    const float* __restrict__ W1, const float* __restrict__ b1,
                    const float* __restrict__ W2, const float* __restrict__ b2,
                    const float* __restrict__ W3, const float* __restrict__ b3,
                    const float* __restrict__ W5, const float* __restrict__ b5,
                    const float* __restrict__ wi, const float* __restrict__ wh,
                    const float* __restrict__ bi, const float* __restrict__ bh,
                    const float* __restrict__ w_end, const float* __restrict__ b_end,
                    const int* __restrict__ capp,
                    float* __restrict__ out, Ctrl* ctrl,
                    float* __restrict__ x0g, float* __restrict__ x1g,
                    float* __restrict__ ypub, float* __restrict__ gxpub) {
  const int tid  = threadIdx.x;
  const int lane = tid & 63;
  const int w    = tid >> 6;
  const int bid  = blockIdx.x;
  const int nbeg = (NN*bid)/NBLK;
  const int nend = (NN*(bid+1))/NBLK;
  const int cnt  = nend - nbeg;          // 9 or 10
  const int r0   = bid*GXROWS;

  __shared__ float  W2L[64*64];             // 16384 B
  __shared__ unsigned short eidxL[EPADCAP]; // 27072 B
  __shared__ unsigned edgeL[EE];            // 37632 B (packed src<<16|dst, CSR build only)
  __shared__ int    offL[NN+1];
  __shared__ int    curL[NN];
  __shared__ float  yF[NN+1];
  __shared__ float  inpF[NN];
  __shared__ float  ghL[192];
  __shared__ float4 f4L[80];
  __shared__ int    wsumL[NWAVE];

  // ---- init gate (one-time per launch; R7-proven protocol) ----
  if (bid == 0) {
    if (tid < HD) { stga(&x0g[DROW*HD + tid], 0.f); stga(&x1g[DROW*HD + tid], 0.f); }
    if (tid == 64) stga(&ypub[NN], 0.f);
    if (tid == 65) stga(&ypub[(NN+1) + NN], 0.f);
    for (int i2 = tid; i2 < NBLK*16; i2 += NTHR) {   // zero xflags (1024 words)
      ((unsigned*)ctrl)[16 + i2] = 0u;
    }
    __syncthreads();
    if (tid == 0) {
      __threadfence();
      __hip_atomic_store(&ctrl->ready, MAGIC, __ATOMIC_RELEASE, __HIP_MEMORY_SCOPE_AGENT);
    }
  } else if (tid == 0) {
    long bail = 0;
    while (__hip_atomic_load(&ctrl->ready, __ATOMIC_RELAXED, __HIP_MEMORY_SCOPE_AGENT) != MAGIC) {
      __builtin_amdgcn_s_sleep(1);
      if (++bail > (1L<<20)) break;
    }
    __threadfence();   // one-time inv; precedes all data reads
  }
  __syncthreads();

  // ---- CSR build: single-pass ingest (all 16 waves), pack edges into LDS ----
  for (int i = tid; i < NN; i += NTHR) curL[i] = 0;
  for (int i = tid; i < 1024; i += NTHR) ((float4*)W2L)[i] = ((const float4*)W2)[i];
  __syncthreads();
  {
    const int4* s4 = (const int4*)src;
    const int4* d4 = (const int4*)dst;
    for (int e4 = tid; e4 < EE/4; e4 += NTHR) {   // EE = 4*2352 exactly
      int4 s = s4[e4], d = d4[e4];
      edgeL[e4*4+0] = (unsigned)((s.x<<16)|d.x); atomicAdd(&curL[d.x],1);
      edgeL[e4*4+1] = (unsigned)((s.y<<16)|d.y); atomicAdd(&curL[d.y],1);
      edgeL[e4*4+2] = (unsigned)((s.z<<16)|d.z); atomicAdd(&curL[d.z],1);
      edgeL[e4*4+3] = (unsigned)((s.w<<16)|d.w); atomicAdd(&curL[d.w],1);
    }
    // tiny prefetch: my 3 wi rows (7 KB) + w_end
    prefetch_region(wi + r0*NN, GXROWS*NN, tid, NTHR);
    prefetch_region(w_end, 64, tid, NTHR);
  }
  __syncthreads();

  // ---- padded exclusive scan (wave-level, 2 stages) ----
  {
    const int n0 = 2*tid, n1 = n0 + 1;
    int d0 = (n0 < NN) ? curL[n0] : 0;
    int d1 = (n1 < NN) ? curL[n1] : 0;
    int p0 = (d0 + 7) & ~7, p1 = (d1 + 7) & ~7;
    int my = p0 + p1;
    int inc = my;
    for (int o = 1; o < 64; o <<= 1) { int u = __shfl_up(inc, o); if (lane >= o) inc += u; }
    if (lane == 63) wsumL[w] = inc;
    __syncthreads();
    if (w == 0 && lane < NWAVE) {
      int s0 = wsumL[lane];
      int is = s0;
      for (int o = 1; o < NWAVE; o <<= 1) { int u = __shfl_up(is, o); if (lane >= o) is += u; }
      wsumL[lane] = is - s0;   // exclusive
    }
    __syncthreads();
    int base = wsumL[w] + inc - my;
    if (n0 < NN) { offL[n0] = base;      curL[n0] = base;      }
    if (n1 < NN) { offL[n1] = base + p0; curL[n1] = base + p0; }
    if (tid == NTHR-1) offL[NN] = base + p0 + p1;
  }
  __syncthreads();
  // ---- fill pass from LDS edge cache (no global re-read) ----
  for (int e4 = tid; e4 < EE/4; e4 += NTHR) {
    uint4 pk = ((const uint4*)edgeL)[e4];
    int p;
    p = atomicAdd(&curL[pk.x & 0xFFFF], 1); eidxL[p] = (unsigned short)(pk.x >> 16);
    p = atomicAdd(&curL[pk.y & 0xFFFF], 1); eidxL[p] = (unsigned short)(pk.y >> 16);
    p = atomicAdd(&curL[pk.z & 0xFFFF], 1); eidxL[p] = (unsigned short)(pk.z >> 16);
    p = atomicAdd(&curL[pk.w & 0xFFFF], 1); eidxL[p] = (unsigned short)(pk.w >> 16);
  }
  __syncthreads();
  {
    const int n0 = 2*tid, n1 = n0 + 1;
    if (n0 < NN) for (int k = curL[n0]; k < offL[n0+1]; ++k) eidxL[k] = (unsigned short)DROW;
    if (n1 < NN) for (int k = curL[n1]; k < offL[n1+1]; ++k) eidxL[k] = (unsigned short)DROW;
  }
  __syncthreads();

  // ---- conv1 on my partition ----
  if (tid < cnt) {
    int n = nbeg + tid;
    int o = offL[n], o1 = offL[n+1];
    float fx=0.f, fy=0.f, fz=0.f, fw2=0.f;
    for (int k = o; k < o1; k += 8) {
      uint4 q = *(const uint4*)(eidxL + k);
      int id[8] = { (int)(q.x & 0xFFFF), (int)(q.x >> 16), (int)(q.y & 0xFFFF), (int)(q.y >> 16),
                    (int)(q.z & 0xFFFF), (int)(q.z >> 16), (int)(q.w & 0xFFFF), (int)(q.w >> 16) };
      float4 tv[8]; float m[8];
      #pragma unroll
      for (int u = 0; u < 8; ++u) {
        int valid = id[u] < NN;
        m[u] = valid ? 1.f : 0.f;
        tv[u] = *(const float4*)(feat + (valid ? id[u] : 0)*4);
      }
      #pragma unroll
      for (int u = 0; u < 8; ++u) { fx += m[u]*tv[u].x; fy += m[u]*tv[u].y; fz += m[u]*tv[u].z; fw2 += m[u]*tv[u].w; }
    }
    f4L[tid] = make_float4(fx, fy, fz, fw2);
  }
  __syncthreads();
  const float W3r = W3[lane];
  for (int i = w; i < cnt; i += NWAVE) {
    int n = nbeg + i; float4 f = f4L[i];
    float v = b1[lane] + f.x*W1[lane] + f.y*W1[64+lane] + f.z*W1[128+lane] + f.w*W1[192+lane];
    v = lrelu(v);
    stga(&x0g[n*HD + lane], v);
    float yv = wredsum(v * W3r);
    if (lane == 0) stga(&ypub[n], yv);   // buffer 0
  }
  barrive(ctrl->xflags, bid, 1u);        // X0 + y0 published

  const float b3v  = b3[0];
  const float b2r  = b2[lane];
  const float bend0 = b_end[0];
  const float wer  = w_end[lane];
  const int cap = capp[0];
  float* xc = x0g;
  float* xn = x1g;

  // GRU state, replicated in registers in EVERY wave (uniform => uniform break)
  float stj = 0.f;      // frozen state component for this lane
  float s_run = 0.f;    // running sigmoid sum
  float fprobr = 0.f;   // last committed prob
  int   nsteps = 0;     // committed step count

  // ---- single-barrier pipelined loop ----
  // Iteration k: have X_k, y_k, gx_{k-1}. GRU(gx_{k-1}) -> stop?; conv2 -> X_{k+1};
  // inp/gx_k -> publish; one barrier. Break at k => final X = X_{k-1} (= xn).
  for (int k = 0; ; ++k) {
    bwait(ctrl->xflags, (unsigned)(k+1));          // X_k, y_k, gx_{k-1} visible
    const float* yp = ypub + (k&1)*(NN+1);
    // issue yF loads early (independent of GRU)
    for (int i = tid; i <= NN; i += NTHR) yF[i] = ldga(&yp[i]);

    if (k >= 1) {
      const float* gxp = gxpub + ((k-1)&1)*192;
      int j = lane;
      float gxr = ldga(&gxp[j]), gxz = ldga(&gxp[64+j]), gxn2 = ldga(&gxp[128+j]);
      if (k == 1) {
        float r  = sigm(gxr + bh[j]);
        float z  = sigm(gxz + bh[64+j]);
        float n2 = tanhf(gxn2 + r*bh[128+j]);
        float st = (1.f - z)*n2;                   // h0 = 0
        stj = st;
        float t2 = wredsum(st * wer);
        float pr = sigm(rdlane(t2,0) + bend0);
        s_run = pr; fprobr = pr; nsteps = 0;
        // gh computed AFTER this iteration's barrive (off critical path)
      } else {
        float r  = sigm(gxr + ghL[j]);
        float z  = sigm(gxz + ghL[64+j]);
        float n2 = tanhf(gxn2 + r*ghL[128+j]);
        float st = (1.f - z)*n2 + z*stj;           // frozen state
        float t2 = wredsum(st * wer);
        float pr = sigm(rdlane(t2,0) + bend0);
        s_run += pr; fprobr = pr; nsteps = k-1;
      }
      if (s_run >= THRESHV || k == cap+1) break;   // uniform everywhere
    }

    // ---- conv2: X_{k+1} = lrelu(conv(X_k, W2)), publish y_{k+1} ----
    // Single node per wave (cnt <= 10 < NWAVE): one gather, one FMA chain.
    if (k < cap) {
      float* ypn = ypub + ((k+1)&1)*(NN+1);
      for (int i = w; i < cnt; i += NWAVE) {
        int n = nbeg + i;
        int o = offL[n], o1 = offL[n+1];
        float acc = 0.f;
        for (int kk = o; kk < o1; kk += 8) {
          uint4 q = *(const uint4*)(eidxL + kk);
          acc += ldga(&xc[(int)(q.x & 0xFFFF)*HD + lane]) + ldga(&xc[(int)(q.x >> 16)*HD + lane]);
          acc += ldga(&xc[(int)(q.y & 0xFFFF)*HD + lane]) + ldga(&xc[(int)(q.y >> 16)*HD + lane]);
          acc += ldga(&xc[(int)(q.z & 0xFFFF)*HD + lane]) + ldga(&xc[(int)(q.z >> 16)*HD + lane]);
          acc += ldga(&xc[(int)(q.w & 0xFFFF)*HD + lane]) + ldga(&xc[(int)(q.w >> 16)*HD + lane]);
        }
        float a0=0.f,a1=0.f,a2=0.f,a3=0.f;
        #pragma unroll
        for (int l = 0; l < 64; l += 4) {
          a0 = fmaf(rdlane(acc,l+0), W2L[(l+0)*64 + lane], a0);
          a1 = fmaf(rdlane(acc,l+1), W2L[(l+1)*64 + lane], a1);
          a2 = fmaf(rdlane(acc,l+2), W2L[(l+2)*64 + lane], a2);
          a3 = fmaf(rdlane(acc,l+3), W2L[(l+3)*64 + lane], a3);
        }
        float v = lrelu(b2r + (a0+a1)+(a2+a3));
        stga(&xn[n*HD + lane], v);
        float yv = wredsum(v * W3r);
        if (lane == 0) stga(&ypn[n], yv);
      }
    }
    __syncthreads();                               // yF complete + conv2 done

    // ---- inp_k: all nodes from yF ----
    for (int n = tid; n < NN; n += NTHR) {
      int o = offL[n], o1 = offL[n+1];
      float a = 0.f;
      for (int kk = o; kk < o1; kk += 8) {
        uint4 q = *(const uint4*)(eidxL + kk);
        a += yF[q.x & 0xFFFF] + yF[q.x >> 16] + yF[q.y & 0xFFFF] + yF[q.y >> 16];
        a += yF[q.z & 0xFFFF] + yF[q.z >> 16] + yF[q.w & 0xFFFF] + yF[q.w >> 16];
      }
      inpF[n] = lrelu(a + b3v);
    }
    __syncthreads();

    // ---- gx_k: my 3 rows -> publish ----
    {
      float* gxp = gxpub + (k&1)*192;
      const float4* inp4 = (const float4*)inpF;   // 147 float4s
      for (int rr = w; rr < GXROWS; rr += NWAVE) {
        const float4* row4 = (const float4*)(wi + (r0 + rr)*NN);
        float p = 0.f;
        #pragma unroll
        for (int kk = 0; kk < 3; ++kk) {
          int c = lane + (kk << 6);
          if (c < 147) {
            float4 a = row4[c], b = inp4[c];
            p += a.x*b.x + a.y*b.y + a.z*b.z + a.w*b.w;
          }
        }
        p = wredsum(p);
        if (lane == 0) stga(&gxp[r0 + rr], p + bi[r0 + rr]);
      }
    }

    barrive(ctrl->xflags, bid, (unsigned)(k+2));   // X_{k+1}, y_{k+1}, gx_k published

    // one-time gh for frozen state, off the critical path (needed first at k=2's
    // GRU, which is behind the next bwait's __syncthreads)
    if (k == 1) {
      for (int rr = w; rr < 192; rr += NWAVE) {
        float p = wredsum(wh[rr*64 + lane] * stj);
        if (lane == 0) ghL[rr] = p + bh[rr];
      }
    }
    { float* t = xc; xc = xn; xn = t; }            // commit X_{k+1}
  }

  // ---- final conv on my partition (final X = X_{k-1} = xn) ----
  float* xf = xn;
  for (int i = w; i < cnt; i += NWAVE) {
    int n = nbeg + i;
    int o = offL[n], o1 = offL[n+1];
    float acc = 0.f;
    for (int k = o; k < o1; k += 8) {
      uint4 q = *(const uint4*)(eidxL + k);
      float t[8];
      t[0] = ldga(&xf[(int)(q.x & 0xFFFF)*HD + lane]); t[1] = ldga(&xf[(int)(q.x >> 16)*HD + lane]);
      t[2] = ldga(&xf[(int)(q.y & 0xFFFF)*HD + lane]); t[3] = ldga(&xf[(int)(q.y >> 16)*HD + lane]);
      t[4] = ldga(&xf[(int)(q.z & 0xFFFF)*HD + lane]); t[5] = ldga(&xf[(int)(q.z >> 16)*HD + lane]);
      t[6] = ldga(&xf[(int)(q.w & 0xFFFF)*HD + lane]); t[7] = ldga(&xf[(int)(q.w >> 16)*HD + lane]);
      #pragma unroll
      for (int u = 0; u < 8; ++u) acc += t[u];
    }
    float p0 = wredsum(acc * W5[lane*3 + 0]);
    float p1 = wredsum(acc * W5[lane*3 + 1]);
    float p2 = wredsum(acc * W5[lane*3 + 2]);
    if (lane == 0) {
      out[n*3 + 0] = p0 + b5[0];
      out[n*3 + 1] = p1 + b5[1];
      out[n*3 + 2] = p2 + b5[2];
    }
  }
  if (bid == 0 && tid == 0) {
    out[NN*3]     = (float)nsteps;  // counter
    out[NN*3 + 1] = fprobr;         // fprob
  }
}

extern "C" void kernel_launch(void* const* d_in, const int* in_sizes, int n_in,
                              void* d_out, int out_size, void* d_ws, size_t ws_size,
                              hipStream_t stream) {
  const float* feat  = (const float*)d_in[0];
  const int*   src   = (const int*)d_in[1];
  const int*   dst   = (const int*)d_in[2];
  const float* W1    = (const float*)d_in[3];
  const float* b1    = (const float*)d_in[4];
  const float* W2    = (const float*)d_in[5];
  const float* b2    = (const float*)d_in[6];
  const float* W3    = (const float*)d_in[7];
  const float* b3    = (const float*)d_in[8];
  const float* W5    = (const float*)d_in[9];
  const float* b5    = (const float*)d_in[10];
  const float* wi    = (const float*)d_in[11];
  const float* wh    = (const float*)d_in[12];
  const float* bi    = (const float*)d_in[13];
  const float* bh    = (const float*)d_in[14];
  const float* w_end = (const float*)d_in[15];
  const float* b_end = (const float*)d_in[16];
  const int*   capp  = (const int*)d_in[17];

  float* out = (float*)d_out;
  char* wsb = (char*)d_ws;
  Ctrl*  ctrl   = (Ctrl*)wsb;                 // 64 + 4096 B at NBLK=64
  float* x0g    = (float*)(wsb + 8192);
  float* x1g    = x0g + (size_t)(NN+1)*HD;
  float* ypub   = x1g + (size_t)(NN+1)*HD;
  float* gxpub  = ypub + 2*(NN+1);

  lastgcn_kernel<<<dim3(NBLK), dim3(NTHR), 0, stream>>>(
      feat, src, dst, W1, b1, W2, b2, W3, b3, W5, b5,
      wi, wh, bi, bh, w_end, b_end, capp, out,
      ctrl, x0g, x1g, ypub, gxpub);
}